// Round 6
// baseline (906.835 us; speedup 1.0000x reference)
//
#include <hip/hip_runtime.h>
#include <math.h>

#define GK 602
#define GH 128
#define GC 41
#define GCP 48     // padded class count for layer-2 aggregate
#define KPAD 608   // 19 k-tiles of 32
#define NKT 19
#define W1FN (NKT * 4096)   // W1F elements
#define W2TN (GCP * 128)    // W2T elements (48 x 128)

typedef __bf16 bf16x8 __attribute__((ext_vector_type(8)));
typedef float f32x16 __attribute__((ext_vector_type(16)));

__device__ __forceinline__ unsigned short f2bf(float f) {
    __bf16 b = (__bf16)f;
    return __builtin_bit_cast(unsigned short, b);
}
__device__ __forceinline__ float bf2f(unsigned short u) {
    return __uint_as_float((unsigned int)u << 16);
}
__device__ __forceinline__ float bflo(unsigned int u) { return __uint_as_float(u << 16); }
__device__ __forceinline__ float bfhi(unsigned int u) { return __uint_as_float(u & 0xffff0000u); }

// direct-to-LDS DMA: HW writes wave-uniform base + lane*size; per-lane lds ptr
// must be linear in lane with stride == size (guide §5 / m97 pattern).
__device__ __forceinline__ void gl_lds16(const float* g, float* l) {
    __builtin_amdgcn_global_load_lds((const __attribute__((address_space(1))) void*)g,
                                     (__attribute__((address_space(3))) void*)l, 16, 0, 0);
}
__device__ __forceinline__ void gl_lds4(const float* g, float* l) {
    __builtin_amdgcn_global_load_lds((const __attribute__((address_space(1))) void*)g,
                                     (__attribute__((address_space(3))) void*)l, 4, 0, 0);
}

// ---------------- CSR build ----------------

__global__ void k_hist(const int* __restrict__ dst, int* __restrict__ counts, int E) {
    int g = blockIdx.x * 256 + threadIdx.x;
    int base = g * 4;
    if (((E & 3) == 0) && (base + 3 < E)) {
        int4 d4 = *(const int4*)(dst + base);
        atomicAdd(&counts[d4.x], 1);
        atomicAdd(&counts[d4.y], 1);
        atomicAdd(&counts[d4.z], 1);
        atomicAdd(&counts[d4.w], 1);
    } else {
#pragma unroll
        for (int j = 0; j < 4; ++j) {
            int e = base + j;
            if (e < E) atomicAdd(&counts[dst[e]], 1);
        }
    }
}

// exclusive scan of counts -> row_ptr, 1024 elems/block, shuffle-based
__global__ void k_scan_a(const int* __restrict__ counts, int* __restrict__ row_ptr,
                         int* __restrict__ bsum, int n) {
    __shared__ int wsum[4];
    int t = threadIdx.x;
    int lane = t & 63;
    int wv = t >> 6;
    int base = blockIdx.x * 1024 + t * 4;
    int v[4];
    int s = 0;
#pragma unroll
    for (int j = 0; j < 4; ++j) {
        int idx = base + j;
        v[j] = (idx < n) ? counts[idx] : 0;
        s += v[j];
    }
    int incl = s;
#pragma unroll
    for (int o = 1; o < 64; o <<= 1) {
        int x = __shfl_up(incl, o);
        if (lane >= o) incl += x;
    }
    if (lane == 63) wsum[wv] = incl;
    __syncthreads();
    int woff = 0;
#pragma unroll
    for (int i = 0; i < 3; ++i) woff += (i < wv) ? wsum[i] : 0;
    if (t == 255) bsum[blockIdx.x] = woff + incl;
    int off = woff + incl - s;
#pragma unroll
    for (int j = 0; j < 4; ++j) {
        int idx = base + j;
        if (idx < n) row_ptr[idx] = off;
        off += v[j];
    }
}

// single-block exclusive scan of bsum (nb <= 256)
__global__ void k_scan_b(int* __restrict__ bsum, int nb) {
    __shared__ int sh[256];
    int t = threadIdx.x;
    int v = (t < nb) ? bsum[t] : 0;
    sh[t] = v;
    __syncthreads();
    for (int o = 1; o < 256; o <<= 1) {
        int x = (t >= o) ? sh[t - o] : 0;
        __syncthreads();
        sh[t] += x;
        __syncthreads();
    }
    if (t < nb) bsum[t] = sh[t] - v;
}

// finalize row_ptr, init cursor, compute dinv (fused)
__global__ void k_scan_c(int* __restrict__ row_ptr, const int* __restrict__ bsum,
                         const int* __restrict__ counts, float* __restrict__ dinv,
                         int* __restrict__ cursor, int n, int E) {
    int i = blockIdx.x * 256 + threadIdx.x;
    if (i < n) {
        int rp = row_ptr[i] + bsum[i >> 10];
        row_ptr[i] = rp;
        cursor[i] = rp;
        dinv[i] = rsqrtf((float)(counts[i] + 1));  // +1 self-loop
    }
    if (i == 0) row_ptr[n] = E;
}

// fill per-edge meta: {src, norm = dinv[src]*dinv[dst]} grouped by dst (CSR order)
__global__ void k_fill(const int* __restrict__ src, const int* __restrict__ dst,
                       const float* __restrict__ dinv,
                       int* __restrict__ cursor, int2* __restrict__ meta, int E) {
    int g = blockIdx.x * 256 + threadIdx.x;
    int base = g * 4;
    if (((E & 3) == 0) && (base + 3 < E)) {
        int4 s4 = *(const int4*)(src + base);
        int4 d4 = *(const int4*)(dst + base);
        int ss[4] = {s4.x, s4.y, s4.z, s4.w};
        int dd[4] = {d4.x, d4.y, d4.z, d4.w};
#pragma unroll
        for (int j = 0; j < 4; ++j) {
            int p = atomicAdd(&cursor[dd[j]], 1);
            float w = dinv[ss[j]] * dinv[dd[j]];
            meta[p] = make_int2(ss[j], __float_as_int(w));
        }
    } else {
#pragma unroll
        for (int j = 0; j < 4; ++j) {
            int e = base + j;
            if (e < E) {
                int s = src[e];
                int d = dst[e];
                int p = atomicAdd(&cursor[d], 1);
                float w = dinv[s] * dinv[d];
                meta[p] = make_int2(s, __float_as_int(w));
            }
        }
    }
}

// ---------------- weight prep (one dispatch) ----------------
// W1F layout (ushort idx): kt*4096 + nt*1024 + h*512 + lane*8 + j
//   element = W1[k][col], col = 32*nt + (lane&31), k = 32*kt + 16*h + 8*(lane>>5) + j
// k >= 602 zero-padded (NaN-safety for A k-overreads: garbage*0 = 0).
// W2T layout: [c][k] fp32, c in [0,48) (rows 41..47 zero), k in [0,128).

__global__ void k_prepW(const float* __restrict__ W1, unsigned short* __restrict__ W1F,
                        const float* __restrict__ W2, float* __restrict__ W2T) {
    int i = blockIdx.x * 256 + threadIdx.x;
    if (i < W1FN) {
        int kt = i >> 12;
        int r  = i & 4095;
        int nt = r >> 10;
        int r2 = r & 1023;
        int bs = r2 >> 9;
        int r3 = r2 & 511;
        int ln = r3 >> 3;
        int j  = r3 & 7;
        int col = 32 * nt + (ln & 31);
        int k   = 32 * kt + 16 * bs + 8 * (ln >> 5) + j;
        float v = (k < GK) ? W1[(size_t)k * GH + col] : 0.f;
        W1F[i] = f2bf(v);
    } else if (i < W1FN + W2TN) {
        int j = i - W1FN;
        int c = j >> 7;
        int k = j & 127;
        W2T[j] = (c < GC) ? W2[k * GC + c] : 0.f;
    }
}

// ---------------- GEMM1 via MFMA bf16: X(M x 602) @ W1 -> Y bf16 (M x 128) ----------------
// Sequential-stream design (harness-verified round 3): block owns 32 CONSECUTIVE
// rows = one contiguous 77056B slab of X. Stage slab linearly to LDS via
// global_load_lds width-16, one barrier, run all 19 k-tiles from LDS. B
// fragments from the L2-resident fragment-ordered W1F table. 2 blocks/CU.

#define SLABF (32 * GK)        // 19264 floats per slab

__global__ __launch_bounds__(256, 2) void k_gemm1_mfma(const float* __restrict__ X,
                                                       const unsigned short* __restrict__ W1F,
                                                       unsigned short* __restrict__ Y, int M) {
    __shared__ float As[SLABF + 16];   // 77056B slab + 64B zeroed pad
    int tid = threadIdx.x;
    int lane = tid & 63;
    int w = tid >> 6;
    int rowBase = blockIdx.x * 32;
    const float* slab = X + (size_t)rowBase * GK;

    // ---- stage: contiguous slab -> LDS (all wave-uniform control flow) ----
#pragma unroll
    for (int r = 0; r < 18; ++r) {
        int c = tid + 256 * r;                 // chunks 0..4607
        gl_lds16(slab + 4 * c, &As[4 * c]);
    }
    if (w < 3) {
        int c = 4608 + (w << 6) + lane;        // chunks 4608..4799
        gl_lds16(slab + 4 * c, &As[4 * c]);
    } else {
        int f = 19200 + lane;                  // floats 19200..19263 (last 256B)
        gl_lds4(slab + f, &As[f]);
    }
    if (tid < 16) As[SLABF + tid] = 0.f;       // finite pad for k-overread rows
    asm volatile("s_waitcnt vmcnt(0)" ::: "memory");
    __syncthreads();

    // ---- compute: all 19 k-tiles from LDS, B from global W1F ----
    int arow = lane & 31;                      // A row within slab
    int kh = 8 * (lane >> 5);                  // 0 or 8
    const float* Ar = &As[arow * GK];
    const unsigned short* Wb = W1F + (size_t)w * 1024 + (size_t)lane * 8;

    f32x16 acc;
#pragma unroll
    for (int i = 0; i < 16; ++i) acc[i] = 0.f;

#pragma unroll
    for (int t = 0; t < NKT; ++t) {
        const unsigned short* Wt = Wb + (size_t)t * 4096;
        bf16x8 b0 = *(const bf16x8*)(Wt);          // k-half 0
        bf16x8 b1 = *(const bf16x8*)(Wt + 512);    // k-half 1
        const float* a0p = Ar + 32 * t + kh;
        float2 p0 = *(const float2*)(a0p + 0);
        float2 p1 = *(const float2*)(a0p + 2);
        float2 p2 = *(const float2*)(a0p + 4);
        float2 p3 = *(const float2*)(a0p + 6);
        const float* a1p = a0p + 16;
        float2 q0 = *(const float2*)(a1p + 0);
        float2 q1 = *(const float2*)(a1p + 2);
        float2 q2 = *(const float2*)(a1p + 4);
        float2 q3 = *(const float2*)(a1p + 6);
        bf16x8 af0, af1;
        af0[0] = (__bf16)p0.x; af0[1] = (__bf16)p0.y;
        af0[2] = (__bf16)p1.x; af0[3] = (__bf16)p1.y;
        af0[4] = (__bf16)p2.x; af0[5] = (__bf16)p2.y;
        af0[6] = (__bf16)p3.x; af0[7] = (__bf16)p3.y;
        af1[0] = (__bf16)q0.x; af1[1] = (__bf16)q0.y;
        af1[2] = (__bf16)q1.x; af1[3] = (__bf16)q1.y;
        af1[4] = (__bf16)q2.x; af1[5] = (__bf16)q2.y;
        af1[6] = (__bf16)q3.x; af1[7] = (__bf16)q3.y;
        acc = __builtin_amdgcn_mfma_f32_32x32x16_bf16(af0, b0, acc, 0, 0, 0);
        acc = __builtin_amdgcn_mfma_f32_32x32x16_bf16(af1, b1, acc, 0, 0, 0);
    }

    // epilogue: C/D layout col=lane&31, row=(reg&3)+8*(reg>>2)+4*(lane>>5)
    int gcol = 32 * w + (lane & 31);
#pragma unroll
    for (int reg = 0; reg < 16; ++reg) {
        int rrow = (reg & 3) + 8 * (reg >> 2) + 4 * (lane >> 5);
        int grow = rowBase + rrow;
        if (grow < M) Y[(size_t)grow * GH + gcol] = f2bf(acc[reg]);
    }
}

// ---------------- fused layer-1 aggregate + relu + (h @ W2) -> G (48-wide bf16) ----------------
// Per wave: gather/accumulate the 128-wide row (2 feats/lane) exactly as before,
// apply b1+relu in fp32, stage the row to a per-wave LDS region (fp32 -- more
// precise than the old bf16 round-trip), then 48 lanes each own one output
// class: acc = sum_k hs[k] * W2T[c][k] via float4 W2T loads (L1-hot, 24.6KB)
// and broadcast ds_read_b128. Rows 41..47 of W2T are zero -> G pad is exact 0.
// Eliminates bufB (51MB traffic) and the separate gemm2t dispatch.

__global__ __launch_bounds__(256) void k_agg1f(const unsigned int* __restrict__ H,
                                               unsigned short* __restrict__ G,
                                               const int* __restrict__ row_ptr,
                                               const int2* __restrict__ meta,
                                               const float* __restrict__ dinv,
                                               const float* __restrict__ bias,
                                               const float* __restrict__ W2T, int n) {
    __shared__ float hs[4][128];
    int wv = threadIdx.x >> 6;
    int lane = threadIdx.x & 63;
    int d = blockIdx.x * 4 + wv;
    if (d >= n) return;
    float dd = dinv[d];
    int beg = row_ptr[d], end = row_ptr[d + 1];
    unsigned int v = H[(size_t)d * 64 + lane];
    float sw = dd * dd;
    float a0 = sw * bflo(v);
    float a1 = sw * bfhi(v);
    int e = beg;
    for (; e + 16 <= end; e += 16) {
        int2 m[16];
        unsigned int u[16];
#pragma unroll
        for (int j = 0; j < 16; ++j) m[j] = meta[e + j];
#pragma unroll
        for (int j = 0; j < 16; ++j) u[j] = H[(size_t)m[j].x * 64 + lane];
#pragma unroll
        for (int j = 0; j < 16; ++j) {
            float wj = __int_as_float(m[j].y);
            a0 = fmaf(wj, bflo(u[j]), a0);
            a1 = fmaf(wj, bfhi(u[j]), a1);
        }
    }
    if (e + 8 <= end) {
        int2 m[8];
        unsigned int u[8];
#pragma unroll
        for (int j = 0; j < 8; ++j) m[j] = meta[e + j];
#pragma unroll
        for (int j = 0; j < 8; ++j) u[j] = H[(size_t)m[j].x * 64 + lane];
#pragma unroll
        for (int j = 0; j < 8; ++j) {
            float wj = __int_as_float(m[j].y);
            a0 = fmaf(wj, bflo(u[j]), a0);
            a1 = fmaf(wj, bfhi(u[j]), a1);
        }
        e += 8;
    }
    if (e + 4 <= end) {
        int2 m[4];
        unsigned int u[4];
#pragma unroll
        for (int j = 0; j < 4; ++j) m[j] = meta[e + j];
#pragma unroll
        for (int j = 0; j < 4; ++j) u[j] = H[(size_t)m[j].x * 64 + lane];
#pragma unroll
        for (int j = 0; j < 4; ++j) {
            float wj = __int_as_float(m[j].y);
            a0 = fmaf(wj, bflo(u[j]), a0);
            a1 = fmaf(wj, bfhi(u[j]), a1);
        }
        e += 4;
    }
    for (; e < end; ++e) {
        int2 m = meta[e];
        unsigned int u = H[(size_t)m.x * 64 + lane];
        float wj = __int_as_float(m.y);
        a0 = fmaf(wj, bflo(u), a0);
        a1 = fmaf(wj, bfhi(u), a1);
    }
    a0 = fmaxf(a0 + bias[2 * lane], 0.f);
    a1 = fmaxf(a1 + bias[2 * lane + 1], 0.f);

    // stage relu'd row (fp32) to this wave's LDS region (intra-wave handoff)
    *(float2*)&hs[wv][2 * lane] = make_float2(a0, a1);
    asm volatile("s_waitcnt lgkmcnt(0)" ::: "memory");
    __builtin_amdgcn_sched_barrier(0);

    // 48 lanes each own one class column of W2T
    if (lane < GCP) {
        const float* wr = W2T + (size_t)lane * 128;
        float s0 = 0.f, s1 = 0.f;
#pragma unroll
        for (int q = 0; q < 16; ++q) {
            float4 wv0 = *(const float4*)(wr + 8 * q);
            float4 wv1 = *(const float4*)(wr + 8 * q + 4);
            float4 h0 = *(const float4*)&hs[wv][8 * q];
            float4 h1 = *(const float4*)&hs[wv][8 * q + 4];
            s0 = fmaf(wv0.x, h0.x, s0); s0 = fmaf(wv0.y, h0.y, s0);
            s0 = fmaf(wv0.z, h0.z, s0); s0 = fmaf(wv0.w, h0.w, s0);
            s1 = fmaf(wv1.x, h1.x, s1); s1 = fmaf(wv1.y, h1.y, s1);
            s1 = fmaf(wv1.z, h1.z, s1); s1 = fmaf(wv1.w, h1.w, s1);
        }
        G[(size_t)d * GCP + lane] = f2bf(s0 + s1);
    }
}

// ---------------- layer-2 aggregate at width 48 + bias + log_softmax, write d_out ----------------

__global__ __launch_bounds__(256) void k_agg2(const unsigned short* __restrict__ G,
                                              float* __restrict__ out,
                                              const int* __restrict__ row_ptr,
                                              const int2* __restrict__ meta,
                                              const float* __restrict__ dinv,
                                              const float* __restrict__ b2, int n) {
    int wv = threadIdx.x >> 6;
    int lane = threadIdx.x & 63;
    int gl = (lane < GCP) ? lane : (GCP - 1);
    int d = blockIdx.x * 4 + wv;
    if (d >= n) return;
    float dd = dinv[d];
    int beg = row_ptr[d], end = row_ptr[d + 1];
    float a = dd * dd * bf2f(G[(size_t)d * GCP + gl]);
    int e = beg;
    for (; e + 16 <= end; e += 16) {
        int2 m[16];
        unsigned short u[16];
#pragma unroll
        for (int j = 0; j < 16; ++j) m[j] = meta[e + j];
#pragma unroll
        for (int j = 0; j < 16; ++j) u[j] = G[(size_t)m[j].x * GCP + gl];
#pragma unroll
        for (int j = 0; j < 16; ++j) a = fmaf(__int_as_float(m[j].y), bf2f(u[j]), a);
    }
    if (e + 8 <= end) {
        int2 m[8];
        unsigned short u[8];
#pragma unroll
        for (int j = 0; j < 8; ++j) m[j] = meta[e + j];
#pragma unroll
        for (int j = 0; j < 8; ++j) u[j] = G[(size_t)m[j].x * GCP + gl];
#pragma unroll
        for (int j = 0; j < 8; ++j) a = fmaf(__int_as_float(m[j].y), bf2f(u[j]), a);
        e += 8;
    }
    if (e + 4 <= end) {
        int2 m[4];
        unsigned short u[4];
#pragma unroll
        for (int j = 0; j < 4; ++j) m[j] = meta[e + j];
#pragma unroll
        for (int j = 0; j < 4; ++j) u[j] = G[(size_t)m[j].x * GCP + gl];
#pragma unroll
        for (int j = 0; j < 4; ++j) a = fmaf(__int_as_float(m[j].y), bf2f(u[j]), a);
        e += 4;
    }
    for (; e < end; ++e) {
        int2 m = meta[e];
        a = fmaf(__int_as_float(m.y), bf2f(G[(size_t)m.x * GCP + gl]), a);
    }
    float logit = (lane < GC) ? (a + b2[lane]) : -INFINITY;
    float mx = logit;
#pragma unroll
    for (int off = 32; off; off >>= 1) mx = fmaxf(mx, __shfl_xor(mx, off));
    float ex = (lane < GC) ? __expf(logit - mx) : 0.f;
    float sm = ex;
#pragma unroll
    for (int off = 32; off; off >>= 1) sm += __shfl_xor(sm, off);
    if (lane < GC) out[(size_t)d * GC + lane] = logit - mx - __logf(sm);
}

// ---------------- launch ----------------

static inline size_t alignup256(size_t x) { return (x + 255) & ~(size_t)255; }

extern "C" void kernel_launch(void* const* d_in, const int* in_sizes, int n_in,
                              void* d_out, int out_size, void* d_ws, size_t ws_size,
                              hipStream_t stream) {
    const float* x  = (const float*)d_in[0];
    const int*   ei = (const int*)d_in[1];
    const float* W1 = (const float*)d_in[2];
    const float* b1 = (const float*)d_in[3];
    const float* W2 = (const float*)d_in[4];
    const float* b2 = (const float*)d_in[5];
    float* out = (float*)d_out;

    const int n = in_sizes[0] / GK;   // 100000
    const int E = in_sizes[1] / 2;    // 1600000
    const int* src = ei;
    const int* dst = ei + E;

    char* w = (char*)d_ws;
    char* p;
    p = w; w += alignup256((size_t)n * 4);            float* dinv  = (float*)p;
    p = w; w += alignup256((size_t)n * 4);            int* counts  = (int*)p;
    p = w; w += alignup256((size_t)n * 4);            int* cursor  = (int*)p;
    p = w; w += alignup256((size_t)(n + 1) * 4);      int* row_ptr = (int*)p;
    p = w; w += alignup256(1024 * 4);                 int* bsum    = (int*)p;
    p = w; w += alignup256((size_t)E * 8);            int2* meta   = (int2*)p;
    p = w; w += alignup256((size_t)GH * KPAD * 2);    unsigned short* W1F = (unsigned short*)p;
    p = w; w += alignup256((size_t)W2TN * 4);         float* W2T = (float*)p;
    p = w; w += alignup256((size_t)n * GH * 2);       unsigned short* bufA = (unsigned short*)p; // bf16 H1
    p = w; w += alignup256((size_t)n * GCP * 2);      unsigned short* G    = (unsigned short*)p; // bf16 relu(H1)@W2

    hipMemsetAsync(counts, 0, (size_t)n * 4, stream);

    int gE4 = (E + 1023) / 1024;
    int gN = (n + 255) / 256;
    int nb = (n + 1023) / 1024;

    k_hist<<<gE4, 256, 0, stream>>>(dst, counts, E);
    k_scan_a<<<nb, 256, 0, stream>>>(counts, row_ptr, bsum, n);
    k_scan_b<<<1, 256, 0, stream>>>(bsum, nb);
    k_scan_c<<<gN, 256, 0, stream>>>(row_ptr, bsum, counts, dinv, cursor, n, E);
    k_fill<<<gE4, 256, 0, stream>>>(src, dst, dinv, cursor, meta, E);

    k_prepW<<<(W1FN + W2TN + 255) / 256, 256, 0, stream>>>(W1, W1F, W2, W2T);
    k_gemm1_mfma<<<(n + 31) / 32, 256, 0, stream>>>(x, W1F, bufA, n);
    k_agg1f<<<(n + 3) / 4, 256, 0, stream>>>((const unsigned int*)bufA, G,
                                             row_ptr, meta, dinv, b1, W2T, n);
    k_agg2<<<(n + 3) / 4, 256, 0, stream>>>(G, out, row_ptr, meta, dinv, b2, n);
}

// Round 7
// 763.894 us; speedup vs baseline: 1.1871x; 1.1871x over previous
//
#include <hip/hip_runtime.h>
#include <math.h>

#define GK 602
#define GH 128
#define GC 41
#define GCP 48     // padded class count for layer-2 aggregate
#define KPAD 608   // 19 k-tiles of 32
#define NKT 19

typedef __bf16 bf16x8 __attribute__((ext_vector_type(8)));
typedef float f32x16 __attribute__((ext_vector_type(16)));

__device__ __forceinline__ unsigned short f2bf(float f) {
    __bf16 b = (__bf16)f;
    return __builtin_bit_cast(unsigned short, b);
}
__device__ __forceinline__ float bf2f(unsigned short u) {
    return __uint_as_float((unsigned int)u << 16);
}
__device__ __forceinline__ float bflo(unsigned int u) { return __uint_as_float(u << 16); }
__device__ __forceinline__ float bfhi(unsigned int u) { return __uint_as_float(u & 0xffff0000u); }

// direct-to-LDS DMA: HW writes wave-uniform base + lane*size; per-lane lds ptr
// must be linear in lane with stride == size (guide §5 / m97 pattern).
__device__ __forceinline__ void gl_lds16(const float* g, float* l) {
    __builtin_amdgcn_global_load_lds((const __attribute__((address_space(1))) void*)g,
                                     (__attribute__((address_space(3))) void*)l, 16, 0, 0);
}
__device__ __forceinline__ void gl_lds4(const float* g, float* l) {
    __builtin_amdgcn_global_load_lds((const __attribute__((address_space(1))) void*)g,
                                     (__attribute__((address_space(3))) void*)l, 4, 0, 0);
}

// ---------------- CSR build ----------------

__global__ void k_hist(const int* __restrict__ dst, int* __restrict__ counts, int E) {
    int g = blockIdx.x * 256 + threadIdx.x;
    int base = g * 4;
    if (((E & 3) == 0) && (base + 3 < E)) {
        int4 d4 = *(const int4*)(dst + base);
        atomicAdd(&counts[d4.x], 1);
        atomicAdd(&counts[d4.y], 1);
        atomicAdd(&counts[d4.z], 1);
        atomicAdd(&counts[d4.w], 1);
    } else {
#pragma unroll
        for (int j = 0; j < 4; ++j) {
            int e = base + j;
            if (e < E) atomicAdd(&counts[dst[e]], 1);
        }
    }
}

// exclusive scan of counts -> row_ptr, 1024 elems/block, shuffle-based
__global__ void k_scan_a(const int* __restrict__ counts, int* __restrict__ row_ptr,
                         int* __restrict__ bsum, int n) {
    __shared__ int wsum[4];
    int t = threadIdx.x;
    int lane = t & 63;
    int wv = t >> 6;
    int base = blockIdx.x * 1024 + t * 4;
    int v[4];
    int s = 0;
#pragma unroll
    for (int j = 0; j < 4; ++j) {
        int idx = base + j;
        v[j] = (idx < n) ? counts[idx] : 0;
        s += v[j];
    }
    int incl = s;
#pragma unroll
    for (int o = 1; o < 64; o <<= 1) {
        int x = __shfl_up(incl, o);
        if (lane >= o) incl += x;
    }
    if (lane == 63) wsum[wv] = incl;
    __syncthreads();
    int woff = 0;
#pragma unroll
    for (int i = 0; i < 3; ++i) woff += (i < wv) ? wsum[i] : 0;
    if (t == 255) bsum[blockIdx.x] = woff + incl;
    int off = woff + incl - s;
#pragma unroll
    for (int j = 0; j < 4; ++j) {
        int idx = base + j;
        if (idx < n) row_ptr[idx] = off;
        off += v[j];
    }
}

// single-block exclusive scan of bsum (nb <= 256)
__global__ void k_scan_b(int* __restrict__ bsum, int nb) {
    __shared__ int sh[256];
    int t = threadIdx.x;
    int v = (t < nb) ? bsum[t] : 0;
    sh[t] = v;
    __syncthreads();
    for (int o = 1; o < 256; o <<= 1) {
        int x = (t >= o) ? sh[t - o] : 0;
        __syncthreads();
        sh[t] += x;
        __syncthreads();
    }
    if (t < nb) bsum[t] = sh[t] - v;
}

// finalize row_ptr, init cursor, compute dinv (fused)
__global__ void k_scan_c(int* __restrict__ row_ptr, const int* __restrict__ bsum,
                         const int* __restrict__ counts, float* __restrict__ dinv,
                         int* __restrict__ cursor, int n, int E) {
    int i = blockIdx.x * 256 + threadIdx.x;
    if (i < n) {
        int rp = row_ptr[i] + bsum[i >> 10];
        row_ptr[i] = rp;
        cursor[i] = rp;
        dinv[i] = rsqrtf((float)(counts[i] + 1));  // +1 self-loop
    }
    if (i == 0) row_ptr[n] = E;
}

// fill per-edge meta: src index only (4B), grouped by dst (CSR order).
// norm is recomposed in the aggregates as dinv[src] * dinv[dst] (dd factored out).
__global__ void k_fill(const int* __restrict__ src, const int* __restrict__ dst,
                       int* __restrict__ cursor, int* __restrict__ meta, int E) {
    int g = blockIdx.x * 256 + threadIdx.x;
    int base = g * 4;
    if (((E & 3) == 0) && (base + 3 < E)) {
        int4 s4 = *(const int4*)(src + base);
        int4 d4 = *(const int4*)(dst + base);
        int ss[4] = {s4.x, s4.y, s4.z, s4.w};
        int dd[4] = {d4.x, d4.y, d4.z, d4.w};
#pragma unroll
        for (int j = 0; j < 4; ++j) {
            int p = atomicAdd(&cursor[dd[j]], 1);
            meta[p] = ss[j];
        }
    } else {
#pragma unroll
        for (int j = 0; j < 4; ++j) {
            int e = base + j;
            if (e < E) {
                int p = atomicAdd(&cursor[dst[e]], 1);
                meta[p] = src[e];
            }
        }
    }
}

// ---------------- W1 -> bf16 fragment-ordered global table ----------------
// W1F layout (ushort idx): kt*4096 + nt*1024 + h*512 + lane*8 + j
//   element = W1[k][col], col = 32*nt + (lane&31), k = 32*kt + 16*h + 8*(lane>>5) + j
// k >= 602 zero-padded (NaN-safety for A k-overreads: garbage*0 = 0).

__global__ void k_prepW1F(const float* __restrict__ W1, unsigned short* __restrict__ W1F) {
    int i = blockIdx.x * 256 + threadIdx.x;
    if (i >= NKT * 4096) return;
    int kt = i >> 12;
    int r  = i & 4095;
    int nt = r >> 10;
    int r2 = r & 1023;
    int bs = r2 >> 9;
    int r3 = r2 & 511;
    int ln = r3 >> 3;
    int j  = r3 & 7;
    int col = 32 * nt + (ln & 31);
    int k   = 32 * kt + 16 * bs + 8 * (ln >> 5) + j;
    float v = (k < GK) ? W1[(size_t)k * GH + col] : 0.f;
    W1F[i] = f2bf(v);
}

// ---------------- GEMM1 via MFMA bf16: X(M x 602) @ W1 -> Y bf16 (M x 128) ----------------
// Sequential-stream design (harness-verified round 3): block owns 32 CONSECUTIVE
// rows = one contiguous 77056B slab of X. Stage slab linearly to LDS via
// global_load_lds width-16, one barrier, run all 19 k-tiles from LDS. B
// fragments from the L2-resident fragment-ordered W1F table. 2 blocks/CU.

#define SLABF (32 * GK)        // 19264 floats per slab

__global__ __launch_bounds__(256, 2) void k_gemm1_mfma(const float* __restrict__ X,
                                                       const unsigned short* __restrict__ W1F,
                                                       unsigned short* __restrict__ Y, int M) {
    __shared__ float As[SLABF + 16];   // 77056B slab + 64B zeroed pad
    int tid = threadIdx.x;
    int lane = tid & 63;
    int w = tid >> 6;
    int rowBase = blockIdx.x * 32;
    const float* slab = X + (size_t)rowBase * GK;

    // ---- stage: contiguous slab -> LDS (all wave-uniform control flow) ----
#pragma unroll
    for (int r = 0; r < 18; ++r) {
        int c = tid + 256 * r;                 // chunks 0..4607
        gl_lds16(slab + 4 * c, &As[4 * c]);
    }
    if (w < 3) {
        int c = 4608 + (w << 6) + lane;        // chunks 4608..4799
        gl_lds16(slab + 4 * c, &As[4 * c]);
    } else {
        int f = 19200 + lane;                  // floats 19200..19263 (last 256B)
        gl_lds4(slab + f, &As[f]);
    }
    if (tid < 16) As[SLABF + tid] = 0.f;       // finite pad for k-overread rows
    asm volatile("s_waitcnt vmcnt(0)" ::: "memory");
    __syncthreads();

    // ---- compute: all 19 k-tiles from LDS, B from global W1F ----
    int arow = lane & 31;                      // A row within slab
    int kh = 8 * (lane >> 5);                  // 0 or 8
    const float* Ar = &As[arow * GK];
    const unsigned short* Wb = W1F + (size_t)w * 1024 + (size_t)lane * 8;

    f32x16 acc;
#pragma unroll
    for (int i = 0; i < 16; ++i) acc[i] = 0.f;

#pragma unroll
    for (int t = 0; t < NKT; ++t) {
        const unsigned short* Wt = Wb + (size_t)t * 4096;
        bf16x8 b0 = *(const bf16x8*)(Wt);          // k-half 0
        bf16x8 b1 = *(const bf16x8*)(Wt + 512);    // k-half 1
        const float* a0p = Ar + 32 * t + kh;
        float2 p0 = *(const float2*)(a0p + 0);
        float2 p1 = *(const float2*)(a0p + 2);
        float2 p2 = *(const float2*)(a0p + 4);
        float2 p3 = *(const float2*)(a0p + 6);
        const float* a1p = a0p + 16;
        float2 q0 = *(const float2*)(a1p + 0);
        float2 q1 = *(const float2*)(a1p + 2);
        float2 q2 = *(const float2*)(a1p + 4);
        float2 q3 = *(const float2*)(a1p + 6);
        bf16x8 af0, af1;
        af0[0] = (__bf16)p0.x; af0[1] = (__bf16)p0.y;
        af0[2] = (__bf16)p1.x; af0[3] = (__bf16)p1.y;
        af0[4] = (__bf16)p2.x; af0[5] = (__bf16)p2.y;
        af0[6] = (__bf16)p3.x; af0[7] = (__bf16)p3.y;
        af1[0] = (__bf16)q0.x; af1[1] = (__bf16)q0.y;
        af1[2] = (__bf16)q1.x; af1[3] = (__bf16)q1.y;
        af1[4] = (__bf16)q2.x; af1[5] = (__bf16)q2.y;
        af1[6] = (__bf16)q3.x; af1[7] = (__bf16)q3.y;
        acc = __builtin_amdgcn_mfma_f32_32x32x16_bf16(af0, b0, acc, 0, 0, 0);
        acc = __builtin_amdgcn_mfma_f32_32x32x16_bf16(af1, b1, acc, 0, 0, 0);
    }

    // epilogue: C/D layout col=lane&31, row=(reg&3)+8*(reg>>2)+4*(lane>>5)
    int gcol = 32 * w + (lane & 31);
#pragma unroll
    for (int reg = 0; reg < 16; ++reg) {
        int rrow = (reg & 3) + 8 * (reg >> 2) + 4 * (lane >> 5);
        int grow = rowBase + rrow;
        if (grow < M) Y[(size_t)grow * GH + gcol] = f2bf(acc[reg]);
    }
}

// ---------------- layer-1 aggregate: 128-wide bf16 gather, unroll-16 MLP ----------------
// out_row = dd * ( sum_{e} dinv[s]*h[s] + dd*h[d] ); dd factored out (meta is src-only).

__global__ __launch_bounds__(256) void k_agg1(const unsigned int* __restrict__ H,
                                              unsigned int* __restrict__ O,
                                              const int* __restrict__ row_ptr,
                                              const int* __restrict__ meta,
                                              const float* __restrict__ dinv,
                                              const float* __restrict__ bias, int n) {
    int wv = threadIdx.x >> 6;
    int lane = threadIdx.x & 63;
    int d = blockIdx.x * 4 + wv;
    if (d >= n) return;
    float dd = dinv[d];
    int beg = row_ptr[d], end = row_ptr[d + 1];
    unsigned int v = H[(size_t)d * 64 + lane];
    float a0 = dd * bflo(v);
    float a1 = dd * bfhi(v);
    int e = beg;
    for (; e + 16 <= end; e += 16) {
        int m[16];
        unsigned int u[16];
        float ws[16];
#pragma unroll
        for (int j = 0; j < 16; ++j) m[j] = meta[e + j];
#pragma unroll
        for (int j = 0; j < 16; ++j) u[j] = H[(size_t)m[j] * 64 + lane];
#pragma unroll
        for (int j = 0; j < 16; ++j) ws[j] = dinv[m[j]];
#pragma unroll
        for (int j = 0; j < 16; ++j) {
            a0 = fmaf(ws[j], bflo(u[j]), a0);
            a1 = fmaf(ws[j], bfhi(u[j]), a1);
        }
    }
    if (e + 8 <= end) {
        int m[8];
        unsigned int u[8];
        float ws[8];
#pragma unroll
        for (int j = 0; j < 8; ++j) m[j] = meta[e + j];
#pragma unroll
        for (int j = 0; j < 8; ++j) u[j] = H[(size_t)m[j] * 64 + lane];
#pragma unroll
        for (int j = 0; j < 8; ++j) ws[j] = dinv[m[j]];
#pragma unroll
        for (int j = 0; j < 8; ++j) {
            a0 = fmaf(ws[j], bflo(u[j]), a0);
            a1 = fmaf(ws[j], bfhi(u[j]), a1);
        }
        e += 8;
    }
    if (e + 4 <= end) {
        int m[4];
        unsigned int u[4];
        float ws[4];
#pragma unroll
        for (int j = 0; j < 4; ++j) m[j] = meta[e + j];
#pragma unroll
        for (int j = 0; j < 4; ++j) u[j] = H[(size_t)m[j] * 64 + lane];
#pragma unroll
        for (int j = 0; j < 4; ++j) ws[j] = dinv[m[j]];
#pragma unroll
        for (int j = 0; j < 4; ++j) {
            a0 = fmaf(ws[j], bflo(u[j]), a0);
            a1 = fmaf(ws[j], bfhi(u[j]), a1);
        }
        e += 4;
    }
    for (; e < end; ++e) {
        int m = meta[e];
        unsigned int u = H[(size_t)m * 64 + lane];
        float wj = dinv[m];
        a0 = fmaf(wj, bflo(u), a0);
        a1 = fmaf(wj, bfhi(u), a1);
    }
    a0 = fmaxf(fmaf(dd, a0, bias[2 * lane]), 0.f);
    a1 = fmaxf(fmaf(dd, a1, bias[2 * lane + 1]), 0.f);
    O[(size_t)d * 64 + lane] = (unsigned int)f2bf(a0) | ((unsigned int)f2bf(a1) << 16);
}

// ---------------- layer-2 transform first: G = relu(H1) @ W2, bf16 out, padded to 48 ----------------

__global__ __launch_bounds__(256) void k_gemm2t(const unsigned int* __restrict__ Hb,
                                                const float* __restrict__ W2,
                                                unsigned short* __restrict__ G, int n) {
    __shared__ float ws[128][GCP];
    for (int i = threadIdx.x; i < 128 * GCP; i += 256) {
        int k = i / GCP;
        int c = i - k * GCP;
        ws[k][c] = (c < GC) ? W2[k * GC + c] : 0.f;
    }
    __syncthreads();
    int r0 = blockIdx.x * 512 + threadIdx.x;
    int r1 = r0 + 256;
    bool v0 = r0 < n, v1 = r1 < n;
    float acc0[GCP], acc1[GCP];
#pragma unroll
    for (int c = 0; c < GCP; ++c) { acc0[c] = 0.f; acc1[c] = 0.f; }
    const uint2* h0 = (const uint2*)(Hb + (size_t)(v0 ? r0 : 0) * 64);
    const uint2* h1 = (const uint2*)(Hb + (size_t)(v1 ? r1 : 0) * 64);
    for (int q = 0; q < 32; ++q) {
        uint2 ua = h0[q];
        uint2 ub = h1[q];
        float va[4] = {bflo(ua.x), bfhi(ua.x), bflo(ua.y), bfhi(ua.y)};
        float vb[4] = {bflo(ub.x), bfhi(ub.x), bflo(ub.y), bfhi(ub.y)};
#pragma unroll
        for (int j = 0; j < 4; ++j) {
            int k = 4 * q + j;
#pragma unroll
            for (int cq = 0; cq < GCP / 4; ++cq) {
                float4 wv = *(const float4*)&ws[k][4 * cq];
                acc0[4 * cq + 0] = fmaf(va[j], wv.x, acc0[4 * cq + 0]);
                acc0[4 * cq + 1] = fmaf(va[j], wv.y, acc0[4 * cq + 1]);
                acc0[4 * cq + 2] = fmaf(va[j], wv.z, acc0[4 * cq + 2]);
                acc0[4 * cq + 3] = fmaf(va[j], wv.w, acc0[4 * cq + 3]);
                acc1[4 * cq + 0] = fmaf(vb[j], wv.x, acc1[4 * cq + 0]);
                acc1[4 * cq + 1] = fmaf(vb[j], wv.y, acc1[4 * cq + 1]);
                acc1[4 * cq + 2] = fmaf(vb[j], wv.z, acc1[4 * cq + 2]);
                acc1[4 * cq + 3] = fmaf(vb[j], wv.w, acc1[4 * cq + 3]);
            }
        }
    }
    if (v0) {
#pragma unroll
        for (int c = 0; c < GCP; ++c) G[(size_t)r0 * GCP + c] = f2bf(acc0[c]);
    }
    if (v1) {
#pragma unroll
        for (int c = 0; c < GCP; ++c) G[(size_t)r1 * GCP + c] = f2bf(acc1[c]);
    }
}

// ---------------- layer-2 aggregate at width 48 + bias + log_softmax, write d_out ----------------
// out = dd * ( sum_{e} dinv[s]*g[s] + dd*g[d] ) + b2, then log_softmax.

__global__ __launch_bounds__(256) void k_agg2(const unsigned short* __restrict__ G,
                                              float* __restrict__ out,
                                              const int* __restrict__ row_ptr,
                                              const int* __restrict__ meta,
                                              const float* __restrict__ dinv,
                                              const float* __restrict__ b2, int n) {
    int wv = threadIdx.x >> 6;
    int lane = threadIdx.x & 63;
    int gl = (lane < GCP) ? lane : (GCP - 1);
    int d = blockIdx.x * 4 + wv;
    if (d >= n) return;
    float dd = dinv[d];
    int beg = row_ptr[d], end = row_ptr[d + 1];
    float a = dd * bf2f(G[(size_t)d * GCP + gl]);
    int e = beg;
    for (; e + 16 <= end; e += 16) {
        int m[16];
        unsigned short u[16];
        float ws[16];
#pragma unroll
        for (int j = 0; j < 16; ++j) m[j] = meta[e + j];
#pragma unroll
        for (int j = 0; j < 16; ++j) u[j] = G[(size_t)m[j] * GCP + gl];
#pragma unroll
        for (int j = 0; j < 16; ++j) ws[j] = dinv[m[j]];
#pragma unroll
        for (int j = 0; j < 16; ++j) a = fmaf(ws[j], bf2f(u[j]), a);
    }
    if (e + 8 <= end) {
        int m[8];
        unsigned short u[8];
        float ws[8];
#pragma unroll
        for (int j = 0; j < 8; ++j) m[j] = meta[e + j];
#pragma unroll
        for (int j = 0; j < 8; ++j) u[j] = G[(size_t)m[j] * GCP + gl];
#pragma unroll
        for (int j = 0; j < 8; ++j) ws[j] = dinv[m[j]];
#pragma unroll
        for (int j = 0; j < 8; ++j) a = fmaf(ws[j], bf2f(u[j]), a);
        e += 8;
    }
    if (e + 4 <= end) {
        int m[4];
        unsigned short u[4];
        float ws[4];
#pragma unroll
        for (int j = 0; j < 4; ++j) m[j] = meta[e + j];
#pragma unroll
        for (int j = 0; j < 4; ++j) u[j] = G[(size_t)m[j] * GCP + gl];
#pragma unroll
        for (int j = 0; j < 4; ++j) ws[j] = dinv[m[j]];
#pragma unroll
        for (int j = 0; j < 4; ++j) a = fmaf(ws[j], bf2f(u[j]), a);
        e += 4;
    }
    for (; e < end; ++e) {
        int m = meta[e];
        a = fmaf(dinv[m], bf2f(G[(size_t)m * GCP + gl]), a);
    }
    float logit = (lane < GC) ? fmaf(dd, a, b2[lane]) : -INFINITY;
    float mx = logit;
#pragma unroll
    for (int off = 32; off; off >>= 1) mx = fmaxf(mx, __shfl_xor(mx, off));
    float ex = (lane < GC) ? __expf(logit - mx) : 0.f;
    float sm = ex;
#pragma unroll
    for (int off = 32; off; off >>= 1) sm += __shfl_xor(sm, off);
    if (lane < GC) out[(size_t)d * GC + lane] = logit - mx - __logf(sm);
}

// ---------------- launch ----------------

static inline size_t alignup256(size_t x) { return (x + 255) & ~(size_t)255; }

extern "C" void kernel_launch(void* const* d_in, const int* in_sizes, int n_in,
                              void* d_out, int out_size, void* d_ws, size_t ws_size,
                              hipStream_t stream) {
    const float* x  = (const float*)d_in[0];
    const int*   ei = (const int*)d_in[1];
    const float* W1 = (const float*)d_in[2];
    const float* b1 = (const float*)d_in[3];
    const float* W2 = (const float*)d_in[4];
    const float* b2 = (const float*)d_in[5];
    float* out = (float*)d_out;

    const int n = in_sizes[0] / GK;   // 100000
    const int E = in_sizes[1] / 2;    // 1600000
    const int* src = ei;
    const int* dst = ei + E;

    char* w = (char*)d_ws;
    char* p;
    p = w; w += alignup256((size_t)n * 4);            float* dinv  = (float*)p;
    p = w; w += alignup256((size_t)n * 4);            int* counts  = (int*)p;
    p = w; w += alignup256((size_t)n * 4);            int* cursor  = (int*)p;
    p = w; w += alignup256((size_t)(n + 1) * 4);      int* row_ptr = (int*)p;
    p = w; w += alignup256(1024 * 4);                 int* bsum    = (int*)p;
    p = w; w += alignup256((size_t)E * 4);            int* meta    = (int*)p;   // src only
    p = w; w += alignup256((size_t)GH * KPAD * 2);    unsigned short* W1F = (unsigned short*)p;
    p = w; w += alignup256((size_t)n * GH * 2);       unsigned short* bufA = (unsigned short*)p; // bf16 H1
    p = w; w += alignup256((size_t)n * GH * 2);       unsigned short* bufB = (unsigned short*)p; // bf16 relu(agg1)
    p = w; w += alignup256((size_t)n * GCP * 2);      unsigned short* G    = (unsigned short*)p; // bf16 H1relu@W2

    hipMemsetAsync(counts, 0, (size_t)n * 4, stream);

    int gE4 = (E + 1023) / 1024;
    int gN = (n + 255) / 256;
    int nb = (n + 1023) / 1024;

    k_hist<<<gE4, 256, 0, stream>>>(dst, counts, E);
    k_scan_a<<<nb, 256, 0, stream>>>(counts, row_ptr, bsum, n);
    k_scan_b<<<1, 256, 0, stream>>>(bsum, nb);
    k_scan_c<<<gN, 256, 0, stream>>>(row_ptr, bsum, counts, dinv, cursor, n, E);
    k_fill<<<gE4, 256, 0, stream>>>(src, dst, cursor, meta, E);

    k_prepW1F<<<(NKT * 4096 + 255) / 256, 256, 0, stream>>>(W1, W1F);
    k_gemm1_mfma<<<(n + 31) / 32, 256, 0, stream>>>(x, W1F, bufA, n);
    k_agg1<<<(n + 3) / 4, 256, 0, stream>>>((const unsigned int*)bufA, (unsigned int*)bufB,
                                            row_ptr, meta, dinv, b1, n);
    k_gemm2t<<<(n + 511) / 512, 256, 0, stream>>>((const unsigned int*)bufB, W2, G, n);
    k_agg2<<<(n + 3) / 4, 256, 0, stream>>>(G, out, row_ptr, meta, dinv, b2, n);
}

// Round 8
// 668.463 us; speedup vs baseline: 1.3566x; 1.1428x over previous
//
#include <hip/hip_runtime.h>
#include <math.h>

#define GK 602
#define GH 128
#define GC 41
#define GCP 48     // padded class count for layer-2 aggregate
#define KPAD 608   // 19 k-tiles of 32
#define NKT 19
#define W1FN (NKT * 4096)   // W1F elements

typedef __bf16 bf16x8 __attribute__((ext_vector_type(8)));
typedef float f32x16 __attribute__((ext_vector_type(16)));

__device__ __forceinline__ unsigned short f2bf(float f) {
    __bf16 b = (__bf16)f;
    return __builtin_bit_cast(unsigned short, b);
}
__device__ __forceinline__ float bf2f(unsigned short u) {
    return __uint_as_float((unsigned int)u << 16);
}
__device__ __forceinline__ float bflo(unsigned int u) { return __uint_as_float(u << 16); }
__device__ __forceinline__ float bfhi(unsigned int u) { return __uint_as_float(u & 0xffff0000u); }

// direct-to-LDS DMA: HW writes wave-uniform base + lane*size; per-lane lds ptr
// must be linear in lane with stride == size (guide §5 / m97 pattern).
__device__ __forceinline__ void gl_lds16(const float* g, float* l) {
    __builtin_amdgcn_global_load_lds((const __attribute__((address_space(1))) void*)g,
                                     (__attribute__((address_space(3))) void*)l, 16, 0, 0);
}
__device__ __forceinline__ void gl_lds4(const float* g, float* l) {
    __builtin_amdgcn_global_load_lds((const __attribute__((address_space(1))) void*)g,
                                     (__attribute__((address_space(3))) void*)l, 4, 0, 0);
}

// ---------------- L1 role-split: prepW1F (blocks < nbPrep) || hist ----------------
// W1F layout (ushort idx): kt*4096 + nt*1024 + h*512 + lane*8 + j
//   element = W1[k][col], col = 32*nt + (lane&31), k = 32*kt + 16*h + 8*(lane>>5) + j
// k >= 602 zero-padded (NaN-safety for A k-overreads: garbage*0 = 0).

__global__ void k_pre(const float* __restrict__ W1, unsigned short* __restrict__ W1F,
                      const int* __restrict__ dst, int* __restrict__ counts,
                      int E, int nbPrep) {
    if ((int)blockIdx.x < nbPrep) {
        int i = blockIdx.x * 256 + threadIdx.x;
        if (i >= W1FN) return;
        int kt = i >> 12;
        int r  = i & 4095;
        int nt = r >> 10;
        int r2 = r & 1023;
        int bs = r2 >> 9;
        int r3 = r2 & 511;
        int ln = r3 >> 3;
        int j  = r3 & 7;
        int col = 32 * nt + (ln & 31);
        int k   = 32 * kt + 16 * bs + 8 * (ln >> 5) + j;
        float v = (k < GK) ? W1[(size_t)k * GH + col] : 0.f;
        W1F[i] = f2bf(v);
    } else {
        int g = (blockIdx.x - nbPrep) * 256 + threadIdx.x;
        int base = g * 4;
        if (((E & 3) == 0) && (base + 3 < E)) {
            int4 d4 = *(const int4*)(dst + base);
            atomicAdd(&counts[d4.x], 1);
            atomicAdd(&counts[d4.y], 1);
            atomicAdd(&counts[d4.z], 1);
            atomicAdd(&counts[d4.w], 1);
        } else {
#pragma unroll
            for (int j2 = 0; j2 < 4; ++j2) {
                int e = base + j2;
                if (e < E) atomicAdd(&counts[dst[e]], 1);
            }
        }
    }
}

// exclusive scan of counts -> row_ptr, 1024 elems/block, shuffle-based
__global__ void k_scan_a(const int* __restrict__ counts, int* __restrict__ row_ptr,
                         int* __restrict__ bsum, int n) {
    __shared__ int wsum[4];
    int t = threadIdx.x;
    int lane = t & 63;
    int wv = t >> 6;
    int base = blockIdx.x * 1024 + t * 4;
    int v[4];
    int s = 0;
#pragma unroll
    for (int j = 0; j < 4; ++j) {
        int idx = base + j;
        v[j] = (idx < n) ? counts[idx] : 0;
        s += v[j];
    }
    int incl = s;
#pragma unroll
    for (int o = 1; o < 64; o <<= 1) {
        int x = __shfl_up(incl, o);
        if (lane >= o) incl += x;
    }
    if (lane == 63) wsum[wv] = incl;
    __syncthreads();
    int woff = 0;
#pragma unroll
    for (int i = 0; i < 3; ++i) woff += (i < wv) ? wsum[i] : 0;
    if (t == 255) bsum[blockIdx.x] = woff + incl;
    int off = woff + incl - s;
#pragma unroll
    for (int j = 0; j < 4; ++j) {
        int idx = base + j;
        if (idx < n) row_ptr[idx] = off;
        off += v[j];
    }
}

// single-block exclusive scan of bsum (nb <= 256)
__global__ void k_scan_b(int* __restrict__ bsum, int nb) {
    __shared__ int sh[256];
    int t = threadIdx.x;
    int v = (t < nb) ? bsum[t] : 0;
    sh[t] = v;
    __syncthreads();
    for (int o = 1; o < 256; o <<= 1) {
        int x = (t >= o) ? sh[t - o] : 0;
        __syncthreads();
        sh[t] += x;
        __syncthreads();
    }
    if (t < nb) bsum[t] = sh[t] - v;
}

// finalize row_ptr, init cursor, compute dinv (fused)
__global__ void k_scan_c(int* __restrict__ row_ptr, const int* __restrict__ bsum,
                         const int* __restrict__ counts, float* __restrict__ dinv,
                         int* __restrict__ cursor, int n, int E) {
    int i = blockIdx.x * 256 + threadIdx.x;
    if (i < n) {
        int rp = row_ptr[i] + bsum[i >> 10];
        row_ptr[i] = rp;
        cursor[i] = rp;
        dinv[i] = rsqrtf((float)(counts[i] + 1));  // +1 self-loop
    }
    if (i == 0) row_ptr[n] = E;
}

// ---------------- L5 role-split: gemm1 (blocks < nbG) || fill ----------------
// gemm1: sequential-stream MFMA design (harness-verified r3/r7): block owns 32
// consecutive rows = one contiguous 77056B slab of X staged linearly to LDS via
// global_load_lds; B fragments from the L2-resident fragment-ordered W1F table.
// fill: per-edge meta {src, norm=dinv[src]*dinv[dst]} grouped by dst (CSR order),
// int4 edge reads. Independent roles, block-uniform branch, no cross-role sync.

#define SLABF (32 * GK)        // 19264 floats per slab

__global__ __launch_bounds__(256, 2) void k_gemm1_fill(
        const float* __restrict__ X, const unsigned short* __restrict__ W1F,
        unsigned short* __restrict__ Y, int M,
        const int* __restrict__ src, const int* __restrict__ dst,
        const float* __restrict__ dinv, int* __restrict__ cursor,
        int2* __restrict__ meta, int E, int nbG) {
    if ((int)blockIdx.x >= nbG) {
        // ---- fill role ----
        int g = (blockIdx.x - nbG) * 256 + threadIdx.x;
        int base = g * 4;
        if (((E & 3) == 0) && (base + 3 < E)) {
            int4 s4 = *(const int4*)(src + base);
            int4 d4 = *(const int4*)(dst + base);
            int ss[4] = {s4.x, s4.y, s4.z, s4.w};
            int dd[4] = {d4.x, d4.y, d4.z, d4.w};
#pragma unroll
            for (int j = 0; j < 4; ++j) {
                int p = atomicAdd(&cursor[dd[j]], 1);
                float w = dinv[ss[j]] * dinv[dd[j]];
                meta[p] = make_int2(ss[j], __float_as_int(w));
            }
        } else {
#pragma unroll
            for (int j = 0; j < 4; ++j) {
                int e = base + j;
                if (e < E) {
                    int s = src[e];
                    int d = dst[e];
                    int p = atomicAdd(&cursor[d], 1);
                    float w = dinv[s] * dinv[d];
                    meta[p] = make_int2(s, __float_as_int(w));
                }
            }
        }
        return;
    }

    // ---- gemm1 role ----
    __shared__ float As[SLABF + 16];   // 77056B slab + 64B zeroed pad
    int tid = threadIdx.x;
    int lane = tid & 63;
    int w = tid >> 6;
    int rowBase = blockIdx.x * 32;
    const float* slab = X + (size_t)rowBase * GK;

#pragma unroll
    for (int r = 0; r < 18; ++r) {
        int c = tid + 256 * r;                 // chunks 0..4607
        gl_lds16(slab + 4 * c, &As[4 * c]);
    }
    if (w < 3) {
        int c = 4608 + (w << 6) + lane;        // chunks 4608..4799
        gl_lds16(slab + 4 * c, &As[4 * c]);
    } else {
        int f = 19200 + lane;                  // floats 19200..19263 (last 256B)
        gl_lds4(slab + f, &As[f]);
    }
    if (tid < 16) As[SLABF + tid] = 0.f;       // finite pad for k-overread rows
    asm volatile("s_waitcnt vmcnt(0)" ::: "memory");
    __syncthreads();

    int arow = lane & 31;                      // A row within slab
    int kh = 8 * (lane >> 5);                  // 0 or 8
    const float* Ar = &As[arow * GK];
    const unsigned short* Wb = W1F + (size_t)w * 1024 + (size_t)lane * 8;

    f32x16 acc;
#pragma unroll
    for (int i = 0; i < 16; ++i) acc[i] = 0.f;

#pragma unroll
    for (int t = 0; t < NKT; ++t) {
        const unsigned short* Wt = Wb + (size_t)t * 4096;
        bf16x8 b0 = *(const bf16x8*)(Wt);          // k-half 0
        bf16x8 b1 = *(const bf16x8*)(Wt + 512);    // k-half 1
        const float* a0p = Ar + 32 * t + kh;
        float2 p0 = *(const float2*)(a0p + 0);
        float2 p1 = *(const float2*)(a0p + 2);
        float2 p2 = *(const float2*)(a0p + 4);
        float2 p3 = *(const float2*)(a0p + 6);
        const float* a1p = a0p + 16;
        float2 q0 = *(const float2*)(a1p + 0);
        float2 q1 = *(const float2*)(a1p + 2);
        float2 q2 = *(const float2*)(a1p + 4);
        float2 q3 = *(const float2*)(a1p + 6);
        bf16x8 af0, af1;
        af0[0] = (__bf16)p0.x; af0[1] = (__bf16)p0.y;
        af0[2] = (__bf16)p1.x; af0[3] = (__bf16)p1.y;
        af0[4] = (__bf16)p2.x; af0[5] = (__bf16)p2.y;
        af0[6] = (__bf16)p3.x; af0[7] = (__bf16)p3.y;
        af1[0] = (__bf16)q0.x; af1[1] = (__bf16)q0.y;
        af1[2] = (__bf16)q1.x; af1[3] = (__bf16)q1.y;
        af1[4] = (__bf16)q2.x; af1[5] = (__bf16)q2.y;
        af1[6] = (__bf16)q3.x; af1[7] = (__bf16)q3.y;
        acc = __builtin_amdgcn_mfma_f32_32x32x16_bf16(af0, b0, acc, 0, 0, 0);
        acc = __builtin_amdgcn_mfma_f32_32x32x16_bf16(af1, b1, acc, 0, 0, 0);
    }

    // epilogue: C/D layout col=lane&31, row=(reg&3)+8*(reg>>2)+4*(lane>>5)
    int gcol = 32 * w + (lane & 31);
#pragma unroll
    for (int reg = 0; reg < 16; ++reg) {
        int rrow = (reg & 3) + 8 * (reg >> 2) + 4 * (lane >> 5);
        int grow = rowBase + rrow;
        if (grow < M) Y[(size_t)grow * GH + gcol] = f2bf(acc[reg]);
    }
}

// ---------------- layer-1 aggregate: 128-wide bf16 gather, unroll-16 MLP (r4 body) ----------------

__global__ __launch_bounds__(256) void k_agg1(const unsigned int* __restrict__ H,
                                              unsigned int* __restrict__ O,
                                              const int* __restrict__ row_ptr,
                                              const int2* __restrict__ meta,
                                              const float* __restrict__ dinv,
                                              const float* __restrict__ bias, int n) {
    int wv = threadIdx.x >> 6;
    int lane = threadIdx.x & 63;
    int d = blockIdx.x * 4 + wv;
    if (d >= n) return;
    float dd = dinv[d];
    int beg = row_ptr[d], end = row_ptr[d + 1];
    unsigned int v = H[(size_t)d * 64 + lane];
    float sw = dd * dd;
    float a0 = sw * bflo(v);
    float a1 = sw * bfhi(v);
    int e = beg;
    for (; e + 16 <= end; e += 16) {
        int2 m[16];
        unsigned int u[16];
#pragma unroll
        for (int j = 0; j < 16; ++j) m[j] = meta[e + j];
#pragma unroll
        for (int j = 0; j < 16; ++j) u[j] = H[(size_t)m[j].x * 64 + lane];
#pragma unroll
        for (int j = 0; j < 16; ++j) {
            float wj = __int_as_float(m[j].y);
            a0 = fmaf(wj, bflo(u[j]), a0);
            a1 = fmaf(wj, bfhi(u[j]), a1);
        }
    }
    if (e + 8 <= end) {
        int2 m[8];
        unsigned int u[8];
#pragma unroll
        for (int j = 0; j < 8; ++j) m[j] = meta[e + j];
#pragma unroll
        for (int j = 0; j < 8; ++j) u[j] = H[(size_t)m[j].x * 64 + lane];
#pragma unroll
        for (int j = 0; j < 8; ++j) {
            float wj = __int_as_float(m[j].y);
            a0 = fmaf(wj, bflo(u[j]), a0);
            a1 = fmaf(wj, bfhi(u[j]), a1);
        }
        e += 8;
    }
    if (e + 4 <= end) {
        int2 m[4];
        unsigned int u[4];
#pragma unroll
        for (int j = 0; j < 4; ++j) m[j] = meta[e + j];
#pragma unroll
        for (int j = 0; j < 4; ++j) u[j] = H[(size_t)m[j].x * 64 + lane];
#pragma unroll
        for (int j = 0; j < 4; ++j) {
            float wj = __int_as_float(m[j].y);
            a0 = fmaf(wj, bflo(u[j]), a0);
            a1 = fmaf(wj, bfhi(u[j]), a1);
        }
        e += 4;
    }
    for (; e < end; ++e) {
        int2 m = meta[e];
        unsigned int u = H[(size_t)m.x * 64 + lane];
        float wj = __int_as_float(m.y);
        a0 = fmaf(wj, bflo(u), a0);
        a1 = fmaf(wj, bfhi(u), a1);
    }
    a0 = fmaxf(a0 + bias[2 * lane], 0.f);
    a1 = fmaxf(a1 + bias[2 * lane + 1], 0.f);
    O[(size_t)d * 64 + lane] = (unsigned int)f2bf(a0) | ((unsigned int)f2bf(a1) << 16);
}

// ---------------- layer-2 transform first: G = relu(H1) @ W2, bf16 out, padded to 48 ----------------

__global__ __launch_bounds__(256) void k_gemm2t(const unsigned int* __restrict__ Hb,
                                                const float* __restrict__ W2,
                                                unsigned short* __restrict__ G, int n) {
    __shared__ float ws[128][GCP];
    for (int i = threadIdx.x; i < 128 * GCP; i += 256) {
        int k = i / GCP;
        int c = i - k * GCP;
        ws[k][c] = (c < GC) ? W2[k * GC + c] : 0.f;
    }
    __syncthreads();
    int r0 = blockIdx.x * 512 + threadIdx.x;
    int r1 = r0 + 256;
    bool v0 = r0 < n, v1 = r1 < n;
    float acc0[GCP], acc1[GCP];
#pragma unroll
    for (int c = 0; c < GCP; ++c) { acc0[c] = 0.f; acc1[c] = 0.f; }
    const uint2* h0 = (const uint2*)(Hb + (size_t)(v0 ? r0 : 0) * 64);
    const uint2* h1 = (const uint2*)(Hb + (size_t)(v1 ? r1 : 0) * 64);
    for (int q = 0; q < 32; ++q) {
        uint2 ua = h0[q];
        uint2 ub = h1[q];
        float va[4] = {bflo(ua.x), bfhi(ua.x), bflo(ua.y), bfhi(ua.y)};
        float vb[4] = {bflo(ub.x), bfhi(ub.x), bflo(ub.y), bfhi(ub.y)};
#pragma unroll
        for (int j = 0; j < 4; ++j) {
            int k = 4 * q + j;
#pragma unroll
            for (int cq = 0; cq < GCP / 4; ++cq) {
                float4 wv = *(const float4*)&ws[k][4 * cq];
                acc0[4 * cq + 0] = fmaf(va[j], wv.x, acc0[4 * cq + 0]);
                acc0[4 * cq + 1] = fmaf(va[j], wv.y, acc0[4 * cq + 1]);
                acc0[4 * cq + 2] = fmaf(va[j], wv.z, acc0[4 * cq + 2]);
                acc0[4 * cq + 3] = fmaf(va[j], wv.w, acc0[4 * cq + 3]);
                acc1[4 * cq + 0] = fmaf(vb[j], wv.x, acc1[4 * cq + 0]);
                acc1[4 * cq + 1] = fmaf(vb[j], wv.y, acc1[4 * cq + 1]);
                acc1[4 * cq + 2] = fmaf(vb[j], wv.z, acc1[4 * cq + 2]);
                acc1[4 * cq + 3] = fmaf(vb[j], wv.w, acc1[4 * cq + 3]);
            }
        }
    }
    if (v0) {
#pragma unroll
        for (int c = 0; c < GCP; ++c) G[(size_t)r0 * GCP + c] = f2bf(acc0[c]);
    }
    if (v1) {
#pragma unroll
        for (int c = 0; c < GCP; ++c) G[(size_t)r1 * GCP + c] = f2bf(acc1[c]);
    }
}

// ---------------- layer-2 aggregate at width 48 + bias + log_softmax, write d_out (r4 body) ----------------

__global__ __launch_bounds__(256) void k_agg2(const unsigned short* __restrict__ G,
                                              float* __restrict__ out,
                                              const int* __restrict__ row_ptr,
                                              const int2* __restrict__ meta,
                                              const float* __restrict__ dinv,
                                              const float* __restrict__ b2, int n) {
    int wv = threadIdx.x >> 6;
    int lane = threadIdx.x & 63;
    int gl = (lane < GCP) ? lane : (GCP - 1);
    int d = blockIdx.x * 4 + wv;
    if (d >= n) return;
    float dd = dinv[d];
    int beg = row_ptr[d], end = row_ptr[d + 1];
    float a = dd * dd * bf2f(G[(size_t)d * GCP + gl]);
    int e = beg;
    for (; e + 16 <= end; e += 16) {
        int2 m[16];
        unsigned short u[16];
#pragma unroll
        for (int j = 0; j < 16; ++j) m[j] = meta[e + j];
#pragma unroll
        for (int j = 0; j < 16; ++j) u[j] = G[(size_t)m[j].x * GCP + gl];
#pragma unroll
        for (int j = 0; j < 16; ++j) a = fmaf(__int_as_float(m[j].y), bf2f(u[j]), a);
    }
    if (e + 8 <= end) {
        int2 m[8];
        unsigned short u[8];
#pragma unroll
        for (int j = 0; j < 8; ++j) m[j] = meta[e + j];
#pragma unroll
        for (int j = 0; j < 8; ++j) u[j] = G[(size_t)m[j].x * GCP + gl];
#pragma unroll
        for (int j = 0; j < 8; ++j) a = fmaf(__int_as_float(m[j].y), bf2f(u[j]), a);
        e += 8;
    }
    if (e + 4 <= end) {
        int2 m[4];
        unsigned short u[4];
#pragma unroll
        for (int j = 0; j < 4; ++j) m[j] = meta[e + j];
#pragma unroll
        for (int j = 0; j < 4; ++j) u[j] = G[(size_t)m[j].x * GCP + gl];
#pragma unroll
        for (int j = 0; j < 4; ++j) a = fmaf(__int_as_float(m[j].y), bf2f(u[j]), a);
        e += 4;
    }
    for (; e < end; ++e) {
        int2 m = meta[e];
        a = fmaf(__int_as_float(m.y), bf2f(G[(size_t)m.x * GCP + gl]), a);
    }
    float logit = (lane < GC) ? (a + b2[lane]) : -INFINITY;
    float mx = logit;
#pragma unroll
    for (int off = 32; off; off >>= 1) mx = fmaxf(mx, __shfl_xor(mx, off));
    float ex = (lane < GC) ? __expf(logit - mx) : 0.f;
    float sm = ex;
#pragma unroll
    for (int off = 32; off; off >>= 1) sm += __shfl_xor(sm, off);
    if (lane < GC) out[(size_t)d * GC + lane] = logit - mx - __logf(sm);
}

// ---------------- launch ----------------

static inline size_t alignup256(size_t x) { return (x + 255) & ~(size_t)255; }

extern "C" void kernel_launch(void* const* d_in, const int* in_sizes, int n_in,
                              void* d_out, int out_size, void* d_ws, size_t ws_size,
                              hipStream_t stream) {
    const float* x  = (const float*)d_in[0];
    const int*   ei = (const int*)d_in[1];
    const float* W1 = (const float*)d_in[2];
    const float* b1 = (const float*)d_in[3];
    const float* W2 = (const float*)d_in[4];
    const float* b2 = (const float*)d_in[5];
    float* out = (float*)d_out;

    const int n = in_sizes[0] / GK;   // 100000
    const int E = in_sizes[1] / 2;    // 1600000
    const int* src = ei;
    const int* dst = ei + E;

    char* w = (char*)d_ws;
    char* p;
    p = w; w += alignup256((size_t)n * 4);            float* dinv  = (float*)p;
    p = w; w += alignup256((size_t)n * 4);            int* counts  = (int*)p;
    p = w; w += alignup256((size_t)n * 4);            int* cursor  = (int*)p;
    p = w; w += alignup256((size_t)(n + 1) * 4);      int* row_ptr = (int*)p;
    p = w; w += alignup256(1024 * 4);                 int* bsum    = (int*)p;
    p = w; w += alignup256((size_t)E * 8);            int2* meta   = (int2*)p;
    p = w; w += alignup256((size_t)GH * KPAD * 2);    unsigned short* W1F = (unsigned short*)p;
    p = w; w += alignup256((size_t)n * GH * 2);       unsigned short* bufA = (unsigned short*)p; // bf16 H1
    p = w; w += alignup256((size_t)n * GH * 2);       unsigned short* bufB = (unsigned short*)p; // bf16 relu(agg1)
    p = w; w += alignup256((size_t)n * GCP * 2);      unsigned short* G    = (unsigned short*)p; // bf16 H1relu@W2

    hipMemsetAsync(counts, 0, (size_t)n * 4, stream);

    int gN = (n + 255) / 256;
    int nb = (n + 1023) / 1024;
    int nbPrep = (W1FN + 255) / 256;          // 304
    int nbHist = (E / 4 + 255) / 256;         // 1563 (E divisible by 4)
    int nbG    = (n + 31) / 32;               // 3125

    k_pre<<<nbPrep + nbHist, 256, 0, stream>>>(W1, W1F, dst, counts, E, nbPrep);
    k_scan_a<<<nb, 256, 0, stream>>>(counts, row_ptr, bsum, n);
    k_scan_b<<<1, 256, 0, stream>>>(bsum, nb);
    k_scan_c<<<gN, 256, 0, stream>>>(row_ptr, bsum, counts, dinv, cursor, n, E);

    k_gemm1_fill<<<nbG + nbHist, 256, 0, stream>>>(x, W1F, bufA, n,
                                                   src, dst, dinv, cursor, meta, E, nbG);
    k_agg1<<<(n + 3) / 4, 256, 0, stream>>>((const unsigned int*)bufA, (unsigned int*)bufB,
                                            row_ptr, meta, dinv, b1, n);
    k_gemm2t<<<(n + 511) / 512, 256, 0, stream>>>((const unsigned int*)bufB, W2, G, n);
    k_agg2<<<(n + 3) / 4, 256, 0, stream>>>(G, out, row_ptr, meta, dinv, b2, n);
}